// Round 3
// baseline (386.590 us; speedup 1.0000x reference)
//
#include <hip/hip_runtime.h>
#include <hip/hip_bf16.h>
#include <cstdint>

#define HIDDEN 1024
#define HEADS 16
#define HDIM 64
#define BATCH 2
#define SEQ 2048

typedef __attribute__((ext_vector_type(8))) short bfrag;   // 8 bf16 (4 VGPRs)
typedef __attribute__((ext_vector_type(4))) float f32x4;   // MFMA C/D

// round-to-nearest-even f32 -> bf16 bits
__device__ inline unsigned short f2bf(float f) {
  unsigned u = __float_as_uint(f);
  return (unsigned short)((u + 0x7FFFu + ((u >> 16) & 1u)) >> 16);
}

// Ootomo split: f ~= hi + lo (hi = RNE bf16 of f, lo = RNE bf16 of residual)
__device__ inline void split2(float f, unsigned short& h, unsigned short& l) {
  unsigned u = __float_as_uint(f);
  unsigned hb = (u + 0x7FFFu + ((u >> 16) & 1u)) & 0xFFFF0000u;
  h = (unsigned short)(hb >> 16);
  l = f2bf(f - __uint_as_float(hb));
}

// 8 floats (scaled) -> hi/lo bfrags
__device__ inline void split8(float4 a, float4 b, float scale, bfrag& hi, bfrag& lo) {
  float v[8] = {a.x, a.y, a.z, a.w, b.x, b.y, b.z, b.w};
  bfrag h, l;
#pragma unroll
  for (int e = 0; e < 8; e++) {
    unsigned short hh, ll;
    split2(v[e] * scale, hh, ll);
    h[e] = (short)hh; l[e] = (short)ll;
  }
  hi = h; lo = l;
}

// ---------------- RoPE cos/sin tables: [S][32] each ----------------
__global__ __launch_bounds__(256) void rope_table_k(float* __restrict__ ctab,
                                                    float* __restrict__ stab) {
  int idx = blockIdx.x * 256 + threadIdx.x;   // S*32 items
  int s = idx >> 5, i = idx & 31;
  float inv = powf(10000.0f, -(float)i / 32.0f);  // 10000^(-2i/64)
  float a = (float)s * inv;
  ctab[idx] = cosf(a);
  stab[idx] = sinf(a);
}

// ---------------- bf16x3 split-precision MFMA GEMM ----------------
// C = A(MxK) @ B(NxK)^T + bias.  tile 128x128, BK=64, 4 waves (2x2),
// each wave 4x4 frags of mfma_f32_16x16x32_bf16; acc += ah*bh + ah*bl + al*bh.
// LDS granule-XOR swizzle (16B granule g of row r at g^(r&7)).
// mode 0: Cout[m][n].  mode 1: scatter qkv to Qb/Kb/Vb [b][h][s][d].
__global__ __launch_bounds__(256, 2) void gemm_mfma3(
    const float* __restrict__ A, const float* __restrict__ B,
    const float* __restrict__ bias, float* __restrict__ Cout,
    float* __restrict__ Qb, float* __restrict__ Kb, float* __restrict__ Vb,
    int N, int K, int mode) {
  __shared__ __align__(16) unsigned short Ah[128 * 64];
  __shared__ __align__(16) unsigned short Al[128 * 64];
  __shared__ __align__(16) unsigned short Bh[128 * 64];
  __shared__ __align__(16) unsigned short Bl[128 * 64];

  const int t = threadIdx.x;
  const int lane = t & 63, wv = t >> 6;
  const int wm = wv >> 1, wn = wv & 1;       // 2x2 wave grid
  const int fr = lane & 15, fg = lane >> 4;  // frag row 0..15, k-granule 0..3
  const int n0 = blockIdx.x * 128, m0 = blockIdx.y * 128;

  f32x4 acc[4][4];
#pragma unroll
  for (int i = 0; i < 4; i++)
#pragma unroll
    for (int j = 0; j < 4; j++) acc[i][j] = (f32x4){0.f, 0.f, 0.f, 0.f};

  // prefetch registers: 4 iters x 8 floats each for A and B
  float4 fA[4][2], fB[4][2];
#pragma unroll
  for (int it = 0; it < 4; it++) {
    int flat = it * 256 + t, r = flat >> 3, g = flat & 7;
    const float* pa = A + (size_t)(m0 + r) * K + g * 8;
    const float* pb = B + (size_t)(n0 + r) * K + g * 8;
    fA[it][0] = *(const float4*)pa; fA[it][1] = *(const float4*)(pa + 4);
    fB[it][0] = *(const float4*)pb; fB[it][1] = *(const float4*)(pb + 4);
  }

  for (int kt = 0; kt < K; kt += 64) {
    __syncthreads();   // previous tile fully consumed
#pragma unroll
    for (int it = 0; it < 4; it++) {
      int flat = it * 256 + t, r = flat >> 3, g = flat & 7;
      int ad = r * 64 + ((g ^ (r & 7)) << 3);   // ushort index, swizzled
      bfrag ha, la, hb, lb;
      split8(fA[it][0], fA[it][1], 1.0f, ha, la);
      split8(fB[it][0], fB[it][1], 1.0f, hb, lb);
      *(bfrag*)&Ah[ad] = ha;
      *(bfrag*)&Al[ad] = la;
      *(bfrag*)&Bh[ad] = hb;
      *(bfrag*)&Bl[ad] = lb;
    }
    __syncthreads();

    // prefetch next K-tile (in flight during MFMA)
    if (kt + 64 < K) {
#pragma unroll
      for (int it = 0; it < 4; it++) {
        int flat = it * 256 + t, r = flat >> 3, g = flat & 7;
        const float* pa = A + (size_t)(m0 + r) * K + kt + 64 + g * 8;
        const float* pb = B + (size_t)(n0 + r) * K + kt + 64 + g * 8;
        fA[it][0] = *(const float4*)pa; fA[it][1] = *(const float4*)(pa + 4);
        fB[it][0] = *(const float4*)pb; fB[it][1] = *(const float4*)(pb + 4);
      }
    }

#pragma unroll
    for (int kk = 0; kk < 2; kk++) {
      bfrag ah[4], al[4], bh[4], bl[4];
#pragma unroll
      for (int i = 0; i < 4; i++) {
        int r = wm * 64 + i * 16 + fr;
        int ad = r * 64 + (((kk * 4 + fg) ^ (r & 7)) << 3);
        ah[i] = *(const bfrag*)&Ah[ad];
        al[i] = *(const bfrag*)&Al[ad];
      }
#pragma unroll
      for (int j = 0; j < 4; j++) {
        int r = wn * 64 + j * 16 + fr;
        int ad = r * 64 + (((kk * 4 + fg) ^ (r & 7)) << 3);
        bh[j] = *(const bfrag*)&Bh[ad];
        bl[j] = *(const bfrag*)&Bl[ad];
      }
#pragma unroll
      for (int i = 0; i < 4; i++)
#pragma unroll
        for (int j = 0; j < 4; j++) {
          acc[i][j] = __builtin_amdgcn_mfma_f32_16x16x32_bf16(ah[i], bh[j], acc[i][j], 0, 0, 0);
          acc[i][j] = __builtin_amdgcn_mfma_f32_16x16x32_bf16(ah[i], bl[j], acc[i][j], 0, 0, 0);
          acc[i][j] = __builtin_amdgcn_mfma_f32_16x16x32_bf16(al[i], bh[j], acc[i][j], 0, 0, 0);
        }
    }
  }

  // epilogue: C/D layout col = lane&15 (=fr), row = fg*4 + reg  [m89-verified]
#pragma unroll
  for (int j = 0; j < 4; j++) {
    const int n = n0 + wn * 64 + j * 16 + fr;
    const float bb = bias[n];
#pragma unroll
    for (int i = 0; i < 4; i++) {
#pragma unroll
      for (int reg = 0; reg < 4; reg++) {
        const int m = m0 + wm * 64 + i * 16 + fg * 4 + reg;
        const float val = acc[i][j][reg] + bb;
        if (mode == 0) {
          Cout[(size_t)m * N + n] = val;
        } else {
          const int which = n >> 10;
          const int h = (n >> 6) & (HEADS - 1);
          const int d = n & (HDIM - 1);
          const int b = m >> 11, s = m & (SEQ - 1);
          float* base = (which == 0) ? Qb : ((which == 1) ? Kb : Vb);
          base[(((size_t)(b * HEADS + h)) * SEQ + s) * HDIM + d] = val;
        }
      }
    }
  }
}

// ---------------- in-place RoPE on Q and K: [b][h][s][d] ----------------
__global__ __launch_bounds__(256) void rope_apply_k(float* __restrict__ Qb,
                                                    float* __restrict__ Kb,
                                                    const float* __restrict__ ctab,
                                                    const float* __restrict__ stab) {
  int idx = blockIdx.x * 256 + threadIdx.x;  // B*H*S*8 items
  float* P = blockIdx.y ? Kb : Qb;
  int c4 = (idx & 7) * 4;
  int row = idx >> 3;           // (b*H + h)*S + s
  int s = row & (SEQ - 1);
  float* p0 = P + (size_t)row * HDIM + c4;
  float4 lo = *(float4*)p0;
  float4 hi = *(float4*)(p0 + 32);
  float4 cc = *(const float4*)(ctab + s * 32 + c4);
  float4 ss = *(const float4*)(stab + s * 32 + c4);
  float4 nlo, nhi;
  nlo.x = lo.x * cc.x - hi.x * ss.x;  nhi.x = hi.x * cc.x + lo.x * ss.x;
  nlo.y = lo.y * cc.y - hi.y * ss.y;  nhi.y = hi.y * cc.y + lo.y * ss.y;
  nlo.z = lo.z * cc.z - hi.z * ss.z;  nhi.z = hi.z * cc.z + lo.z * ss.z;
  nlo.w = lo.w * cc.w - hi.w * ss.w;  nhi.w = hi.w * cc.w + lo.w * ss.w;
  *(float4*)p0 = nlo;
  *(float4*)(p0 + 32) = nhi;
}

// ---------------- MFMA flash attention, bf16x3 ----------------
// 256 thr = 4 waves. Q-block 128 rows (32/wave), K-tile 64 keys.
// Swapped QK^T: S^T = K*Q^T so each lane owns q=lane&15's scores.
// P through LDS [q][key] hi/lo; PV unswapped with Vt[d][key] staged transposed.
__global__ __launch_bounds__(256, 2) void attn_mfma(
    const float* __restrict__ Qb, const float* __restrict__ Kb,
    const float* __restrict__ Vb, float* __restrict__ Ob) {
  __shared__ __align__(16) unsigned short Kh[64 * 64], Kl[64 * 64];
  __shared__ __align__(16) unsigned short Vth[64 * 64], Vtl[64 * 64];
  __shared__ __align__(16) unsigned short Ph[128 * 64], Pl[128 * 64];

  const int t = threadIdx.x;
  const int lane = t & 63, w = t >> 6;
  const int fr = lane & 15, fg = lane >> 4;
  const int q0 = blockIdx.x * 128;
  const int h = blockIdx.y, b = blockIdx.z;
  const size_t hb = ((size_t)(b * HEADS + h)) * SEQ * HDIM;
  const float* Qp = Qb + hb;
  const float* Kp = Kb + hb;
  const float* Vp = Vb + hb;

  // Q fragments in registers (B-operand: lane&15 = q, fg*8+e = d), scale 1/8
  bfrag qh[2][2], ql[2][2];   // [qf][kk]
#pragma unroll
  for (int qf = 0; qf < 2; qf++)
#pragma unroll
    for (int kk = 0; kk < 2; kk++) {
      const float* p = Qp + (size_t)(q0 + w * 32 + qf * 16 + fr) * HDIM + kk * 32 + fg * 8;
      split8(*(const float4*)p, *(const float4*)(p + 4), 0.125f, qh[qf][kk], ql[qf][kk]);
    }

  f32x4 Oacc[2][4];
#pragma unroll
  for (int qf = 0; qf < 2; qf++)
#pragma unroll
    for (int df = 0; df < 4; df++) Oacc[qf][df] = (f32x4){0.f, 0.f, 0.f, 0.f};
  float m_i[2] = {-1e30f, -1e30f}, l_i[2] = {0.f, 0.f};

  for (int kt = 0; kt < SEQ; kt += 64) {
    __syncthreads();   // previous K/V tiles fully consumed
    // stage K [key][d] hi/lo, granule swizzle g^(key&7)
#pragma unroll
    for (int c = 0; c < 2; c++) {
      int flat = c * 256 + t, row = flat >> 3, g = flat & 7;
      const float* p = Kp + (size_t)(kt + row) * HDIM + g * 8;
      bfrag hh, ll;
      split8(*(const float4*)p, *(const float4*)(p + 4), 1.0f, hh, ll);
      int ad = row * 64 + ((g ^ (row & 7)) << 3);
      *(bfrag*)&Kh[ad] = hh;
      *(bfrag*)&Kl[ad] = ll;
    }
    // stage V transposed: Vt[d][key], granule swizzle ^((d&7)^(d>>3))
#pragma unroll
    for (int c = 0; c < 2; c++) {
      int flat = c * 256 + t, key = flat >> 3, dq = flat & 7;
      const float* p = Vp + (size_t)(kt + key) * HDIM + dq * 8;
      float4 x0 = *(const float4*)p, x1 = *(const float4*)(p + 4);
      float v[8] = {x0.x, x0.y, x0.z, x0.w, x1.x, x1.y, x1.z, x1.w};
#pragma unroll
      for (int e = 0; e < 8; e++) {
        int d = dq * 8 + e;
        unsigned short hh, ll;
        split2(v[e], hh, ll);
        int gs = ((key >> 3) ^ (d & 7) ^ ((d >> 3) & 7)) & 7;
        int ad = d * 64 + gs * 8 + (key & 7);
        Vth[ad] = hh;
        Vtl[ad] = ll;
      }
    }
    __syncthreads();

    // QK^T (swapped): sacc[ki][qf] = S^T block, key = 16ki+4fg+reg, q = qf*16+fr
    f32x4 sacc[4][2];
#pragma unroll
    for (int ki = 0; ki < 4; ki++)
#pragma unroll
      for (int qf = 0; qf < 2; qf++) sacc[ki][qf] = (f32x4){0.f, 0.f, 0.f, 0.f};
#pragma unroll
    for (int kk = 0; kk < 2; kk++) {
      bfrag kh[4], kl[4];
#pragma unroll
      for (int ki = 0; ki < 4; ki++) {
        int row = ki * 16 + fr;
        int ad = row * 64 + (((4 * kk + fg) ^ (row & 7)) << 3);
        kh[ki] = *(const bfrag*)&Kh[ad];
        kl[ki] = *(const bfrag*)&Kl[ad];
      }
#pragma unroll
      for (int ki = 0; ki < 4; ki++)
#pragma unroll
        for (int qf = 0; qf < 2; qf++) {
          sacc[ki][qf] = __builtin_amdgcn_mfma_f32_16x16x32_bf16(kh[ki], qh[qf][kk], sacc[ki][qf], 0, 0, 0);
          sacc[ki][qf] = __builtin_amdgcn_mfma_f32_16x16x32_bf16(kh[ki], ql[qf][kk], sacc[ki][qf], 0, 0, 0);
          sacc[ki][qf] = __builtin_amdgcn_mfma_f32_16x16x32_bf16(kl[ki], qh[qf][kk], sacc[ki][qf], 0, 0, 0);
        }
    }

    // online softmax per q-fragment; lane's q = qf*16 + fr
#pragma unroll
    for (int qf = 0; qf < 2; qf++) {
      float mm = -1e30f;
#pragma unroll
      for (int ki = 0; ki < 4; ki++)
#pragma unroll
        for (int r = 0; r < 4; r++) mm = fmaxf(mm, sacc[ki][qf][r]);
      mm = fmaxf(mm, __shfl_xor(mm, 16));
      mm = fmaxf(mm, __shfl_xor(mm, 32));
      float mn = fmaxf(m_i[qf], mm);
      float alpha = __expf(m_i[qf] - mn);
      m_i[qf] = mn;
      float rs = 0.f;
      float pv[4][4];
#pragma unroll
      for (int ki = 0; ki < 4; ki++)
#pragma unroll
        for (int r = 0; r < 4; r++) {
          float p = __expf(sacc[ki][qf][r] - mn);
          pv[ki][r] = p;
          rs += p;
        }
      rs += __shfl_xor(rs, 16);
      rs += __shfl_xor(rs, 32);
      l_i[qf] = l_i[qf] * alpha + rs;

      // write P hi/lo: rows [q][key], b64 of 4 packed keys, swizzled
      int qrow = w * 32 + qf * 16 + fr;
#pragma unroll
      for (int ki = 0; ki < 4; ki++) {
        unsigned short hh[4], ll[4];
#pragma unroll
        for (int r = 0; r < 4; r++) split2(pv[ki][r], hh[r], ll[r]);
        int key0 = ki * 16 + 4 * fg;
        int ads = qrow * 64 + (((key0 >> 3) ^ (qrow & 7)) << 3) + (key0 & 7);
        *(uint2*)&Ph[ads] = make_uint2((unsigned)hh[0] | ((unsigned)hh[1] << 16),
                                       (unsigned)hh[2] | ((unsigned)hh[3] << 16));
        *(uint2*)&Pl[ads] = make_uint2((unsigned)ll[0] | ((unsigned)ll[1] << 16),
                                       (unsigned)ll[2] | ((unsigned)ll[3] << 16));
      }
      // rescale O accs (their q = qf*16 + 4fg + reg -> fetch alpha from lane 4fg+reg)
      float ar[4];
#pragma unroll
      for (int r = 0; r < 4; r++) ar[r] = __shfl(alpha, 4 * fg + r);
#pragma unroll
      for (int df = 0; df < 4; df++)
#pragma unroll
        for (int r = 0; r < 4; r++) Oacc[qf][df][r] *= ar[r];
    }

    // PV (unswapped): A = P rows (same-wave RAW through LDS), B = Vt rows
#pragma unroll
    for (int kk = 0; kk < 2; kk++) {
      bfrag pa[2], pb[2], vh[4], vl[4];
#pragma unroll
      for (int qf = 0; qf < 2; qf++) {
        int qrow = w * 32 + qf * 16 + fr;
        int ad = qrow * 64 + (((4 * kk + fg) ^ (qrow & 7)) << 3);
        pa[qf] = *(const bfrag*)&Ph[ad];
        pb[qf] = *(const bfrag*)&Pl[ad];
      }
#pragma unroll
      for (int df = 0; df < 4; df++) {
        int d = df * 16 + fr;
        int gs = ((4 * kk + fg) ^ (d & 7) ^ ((d >> 3) & 7)) & 7;
        int ad = d * 64 + gs * 8;
        vh[df] = *(const bfrag*)&Vth[ad];
        vl[df] = *(const bfrag*)&Vtl[ad];
      }
#pragma unroll
      for (int qf = 0; qf < 2; qf++)
#pragma unroll
        for (int df = 0; df < 4; df++) {
          Oacc[qf][df] = __builtin_amdgcn_mfma_f32_16x16x32_bf16(pa[qf], vh[df], Oacc[qf][df], 0, 0, 0);
          Oacc[qf][df] = __builtin_amdgcn_mfma_f32_16x16x32_bf16(pa[qf], vl[df], Oacc[qf][df], 0, 0, 0);
          Oacc[qf][df] = __builtin_amdgcn_mfma_f32_16x16x32_bf16(pb[qf], vh[df], Oacc[qf][df], 0, 0, 0);
        }
    }
  }

  // epilogue: O[q][d] / l, write Ob[b][s][h][d]; lane's q = qf*16+4fg+reg, d = df*16+fr
#pragma unroll
  for (int qf = 0; qf < 2; qf++) {
    float lr[4];
#pragma unroll
    for (int r = 0; r < 4; r++) lr[r] = 1.0f / __shfl(l_i[qf], 4 * fg + r);
#pragma unroll
    for (int df = 0; df < 4; df++)
#pragma unroll
      for (int r = 0; r < 4; r++) {
        int s = q0 + w * 32 + qf * 16 + 4 * fg + r;
        int d = df * 16 + fr;
        Ob[(((size_t)(b * SEQ + s)) * HEADS + h) * HDIM + d] = Oacc[qf][df][r] * lr[r];
      }
  }
}

extern "C" void kernel_launch(void* const* d_in, const int* in_sizes, int n_in,
                              void* d_out, int out_size, void* d_ws, size_t ws_size,
                              hipStream_t stream) {
  const float* x    = (const float*)d_in[0];
  const float* Wqkv = (const float*)d_in[1];
  const float* bqkv = (const float*)d_in[2];
  const float* Wout = (const float*)d_in[3];
  const float* bout = (const float*)d_in[4];
  float* out = (float*)d_out;

  float* ws = (float*)d_ws;
  const size_t HSZ = (size_t)BATCH * HEADS * SEQ * HDIM;  // 4,194,304
  float* ctab = ws;
  float* stab = ctab + SEQ * 32;
  float* Qb = stab + SEQ * 32;
  float* Kb = Qb + HSZ;
  float* Vb = Kb + HSZ;
  float* Ab = Vb + HSZ;

  hipLaunchKernelGGL(rope_table_k, dim3(SEQ * 32 / 256), dim3(256), 0, stream,
                     ctab, stab);
  hipLaunchKernelGGL(gemm_mfma3, dim3(3 * HIDDEN / 128, BATCH * SEQ / 128),
                     dim3(256), 0, stream,
                     x, Wqkv, bqkv, (float*)nullptr, Qb, Kb, Vb,
                     3 * HIDDEN, HIDDEN, 1);
  hipLaunchKernelGGL(rope_apply_k, dim3(BATCH * HEADS * SEQ * 8 / 256, 2),
                     dim3(256), 0, stream, Qb, Kb, ctab, stab);
  hipLaunchKernelGGL(attn_mfma, dim3(SEQ / 128, HEADS, BATCH), dim3(256), 0, stream,
                     Qb, Kb, Vb, Ab);
  hipLaunchKernelGGL(gemm_mfma3, dim3(HIDDEN / 128, BATCH * SEQ / 128),
                     dim3(256), 0, stream,
                     Ab, Wout, bout, out, (float*)nullptr, (float*)nullptr,
                     (float*)nullptr, HIDDEN, HIDDEN, 0);
}